// Round 16
// baseline (631.153 us; speedup 1.0000x reference)
//
#include <hip/hip_runtime.h>

// VQ codebook nearest-neighbor: xs [32768,512] f32, W [8192,512] f32
// out[i] = W[argmin_j ||xs_i - W_j||^2]
//
// R16: R13's proven i8 dist kernel (257us, 0 conflicts) emitting per-block
//      BEST-3; tail = reduce (enqueue in-band top-3 members; marker only if
//      block's 3rd in band -> hidden-4th possible, ~5 markers total) +
//      tiny exact rescan + flat wave-per-entry exact-f32 fixup (atomicMin).
//      BAND 6.8 = 5.9 sigma of int8 pair error.

#define M_TOK 32768
#define N_EMB 8192
#define D_K   512
#define WOFF  2048.0f
#define QMASK 0xFFFFFF80u     // 7 low bits = local col (128-wide tile)
#define BAND  6.8f
#define NT    8               // K-tiles of 64 (i8)
#define SCALE 22.6786f        // 127/5.6
#define M2C   (-2.0f / (SCALE * SCALE))
#define QCAP  1048576
#define MCAP  65536

typedef __attribute__((ext_vector_type(4))) int   i32x4;
typedef unsigned long long u64;
typedef unsigned int u32;

__device__ __forceinline__ void gload16(const void* g, void* l) {
  __builtin_amdgcn_global_load_lds(
      (const __attribute__((address_space(1))) unsigned int*)g,
      (__attribute__((address_space(3))) unsigned int*)l, 16, 0, 0);
}

__device__ __forceinline__ u32 map_f(float f) {   // exact order-preserving
  u32 u = __float_as_uint(f);
  return u ^ ((u & 0x80000000u) ? 0xFFFFFFFFu : 0x80000000u);
}
__device__ __forceinline__ float qval(u32 key) {  // quantized approx value
  return __uint_as_float(key & QMASK) - WOFF;
}
__device__ __forceinline__ int q8(float x) {
  int v = __float2int_rn(x * SCALE);
  return v < -127 ? -127 : (v > 127 ? 127 : v);
}
__device__ __forceinline__ int dp4(int a, int b) {
  int s = 0;
  #pragma unroll
  for (int i = 0; i < 4; ++i)
    s += ((a << (24 - 8 * i)) >> 24) * ((b << (24 - 8 * i)) >> 24);
  return s;
}
// merge two sorted triples -> first 3 of union (R3-proven logic, u32)
__device__ __forceinline__ void merge3(u32& a1, u32& a2, u32& a3, u32 b1, u32 b2, u32 b3) {
  bool aw = a1 <= b1;
  u32 m1 = aw ? a1 : b1;
  u32 h2 = aw ? a2 : b2, h3 = aw ? a3 : b3;
  u32 l1 = aw ? b1 : a1, l2 = aw ? b2 : a2;
  u32 m2 = h2 <= l1 ? h2 : l1;
  u32 m3 = (h2 <= l1) ? (h3 <= l1 ? h3 : l1) : (h2 <= l2 ? h2 : l2);
  a1 = m1; a2 = m2; a3 = m3;
}

// ---------------- X: f32 -> i8 ----------------
__global__ __launch_bounds__(256) void quant_x_kernel(const float* __restrict__ src,
                                                      char* __restrict__ dst, int n16) {
  int e = blockIdx.x * 256 + threadIdx.x;
  if (e >= n16) return;
  const float4* s4 = (const float4*)src + (size_t)e * 4;
  char out[16];
  #pragma unroll
  for (int i = 0; i < 4; ++i) {
    float4 v = s4[i];
    out[i * 4 + 0] = (char)q8(v.x);
    out[i * 4 + 1] = (char)q8(v.y);
    out[i * 4 + 2] = (char)q8(v.z);
    out[i * 4 + 3] = (char)q8(v.w);
  }
  ((int4*)dst)[e] = *(const int4*)out;
}

// ---------------- W: quantize + exact ||w||^2, zero counters ----------------
__global__ __launch_bounds__(256) void quant_w_kernel(const float* __restrict__ w,
                                                      char* __restrict__ Wq,
                                                      float* __restrict__ wnorm,
                                                      int* __restrict__ cnts) {
  if (blockIdx.x == 0 && threadIdx.x == 0) { cnts[0] = 0; cnts[1] = 0; }
  const int row  = blockIdx.x * 4 + (threadIdx.x >> 6);
  const int lane = threadIdx.x & 63;
  const float4* wr = (const float4*)(w + (size_t)row * D_K);
  float4 v0 = wr[lane * 2], v1 = wr[lane * 2 + 1];
  char out[8];
  out[0] = (char)q8(v0.x); out[1] = (char)q8(v0.y);
  out[2] = (char)q8(v0.z); out[3] = (char)q8(v0.w);
  out[4] = (char)q8(v1.x); out[5] = (char)q8(v1.y);
  out[6] = (char)q8(v1.z); out[7] = (char)q8(v1.w);
  *(int2*)(Wq + (size_t)row * D_K + lane * 8) = *(const int2*)out;
  float s = v0.x*v0.x + v0.y*v0.y + v0.z*v0.z + v0.w*v0.w
          + v1.x*v1.x + v1.y*v1.y + v1.z*v1.z + v1.w*v1.w;
  #pragma unroll
  for (int off = 32; off; off >>= 1) s += __shfl_xor(s, off);
  if (lane == 0) wnorm[row] = s;
}

// ---------------- i8 approx distance + per-block best-3 ----------------
// Main loop identical to R13 (257us, 0 conflicts). Epilogue emits best-3.
__global__ __launch_bounds__(256, 3) void dist_mfma_kernel(
    const char* __restrict__ Xq, const char* __restrict__ Wq,
    const float* __restrict__ wnorm, uint4* __restrict__ partials) {
  __shared__ char smem[32768];   // buf b at b*16384: [A 8KB | B 8KB]

  int bid = (int)blockIdx.x;
  const int swz = (bid & 7) * 2048 + (bid >> 3);   // XCD swizzle (16384 % 8 == 0)
  const int rt = swz & 255, ct = swz >> 8;          // rt fast -> B-panel L2-hot
  const int row0 = rt * 128, col0 = ct * 128;

  const int tid  = threadIdx.x;
  const int w    = tid >> 6, lane = tid & 63;
  const int wr   = w >> 1,  wc   = w & 1;           // 2x2 wave grid
  const int g    = lane >> 4, cl = lane & 15;

  const char* gA = Xq + (size_t)row0 * D_K;         // row = 512 B
  const char* gB = Wq + (size_t)col0 * D_K;

  int srcoff[2];
  #pragma unroll
  for (int q = 0; q < 2; ++q) {
    const int c = q * 256 + tid;
    const int r = c >> 2;
    srcoff[q] = r * 512 + (((c & 3) ^ ((r >> 1) & 3)) * 16);
  }

  int offA[4], offB[4];
  #pragma unroll
  for (int m = 0; m < 4; ++m) {
    const int rl = wr * 64 + m * 16 + cl;
    offA[m] = rl * 64 + ((g ^ ((rl >> 1) & 3)) * 16);
  }
  #pragma unroll
  for (int n = 0; n < 4; ++n) {
    const int rl = wc * 64 + n * 16 + cl;
    offB[n] = 8192 + rl * 64 + ((g ^ ((rl >> 1) & 3)) * 16);
  }

  #define STG(bo, kt)                                                          \
    { _Pragma("unroll") for (int q = 0; q < 2; ++q)                            \
        gload16(gA + srcoff[q] + (kt) * 64,                                    \
                smem + (bo) + q * 4096 + w * 1024);                            \
      _Pragma("unroll") for (int q = 0; q < 2; ++q)                            \
        gload16(gB + srcoff[q] + (kt) * 64,                                    \
                smem + (bo) + 8192 + q * 4096 + w * 1024); }

  i32x4 acc[4][4];
  #pragma unroll
  for (int i = 0; i < 4; i++)
    #pragma unroll
    for (int j = 0; j < 4; j++) acc[i][j] = (i32x4)(0);

  STG(0, 0);
  __syncthreads();

  for (int t = 0; t < NT; ++t) {
    const int rb = (t & 1) * 16384, sb = rb ^ 16384;
    if (t < NT - 1) STG(sb, t + 1);

    i32x4 a[4], b[4];
    #pragma unroll
    for (int m = 0; m < 4; ++m) a[m] = *(const i32x4*)(smem + rb + offA[m]);
    #pragma unroll
    for (int n = 0; n < 4; ++n) b[n] = *(const i32x4*)(smem + rb + offB[n]);

    #pragma unroll
    for (int m = 0; m < 4; ++m)
      #pragma unroll
      for (int n = 0; n < 4; ++n)
        acc[m][n] = __builtin_amdgcn_mfma_i32_16x16x64_i8(a[m], b[n], acc[m][n], 0, 0, 0);

    __syncthreads();
  }
  #undef STG

  float wnp[4];
  u32 colb[4];
  #pragma unroll
  for (int n = 0; n < 4; ++n) {
    const int colL = wc * 64 + n * 16 + cl;
    wnp[n]  = wnorm[col0 + colL] + WOFF;
    colb[n] = (u32)colL;
  }

  uint4* cmb = (uint4*)smem;   // [128 rows][2 wc] = 4KB (loop fully drained)

  #pragma unroll
  for (int m = 0; m < 4; ++m) {
    #pragma unroll
    for (int r = 0; r < 4; ++r) {
      float s0 = fmaf((float)acc[m][0][r], M2C, wnp[0]);
      float s1 = fmaf((float)acc[m][1][r], M2C, wnp[1]);
      float s2 = fmaf((float)acc[m][2][r], M2C, wnp[2]);
      float s3 = fmaf((float)acc[m][3][r], M2C, wnp[3]);
      u32 k0 = (__float_as_uint(s0) & QMASK) | colb[0];
      u32 k1 = (__float_as_uint(s1) & QMASK) | colb[1];
      u32 k2 = (__float_as_uint(s2) & QMASK) | colb[2];
      u32 k3 = (__float_as_uint(s3) & QMASK) | colb[3];
      // best-3 of 4: {c1} U {m1,m2} (global max excluded)
      u32 pa1 = min(k0, k1), pa2 = max(k0, k1);
      u32 pb1 = min(k2, k3), pb2 = max(k2, k3);
      u32 c1 = min(pa1, pb1);
      u32 m1 = max(pa1, pb1), m2 = min(pa2, pb2);
      u32 c2 = min(m1, m2), c3 = max(m1, m2);
      #pragma unroll
      for (int off = 1; off < 16; off <<= 1) {
        u32 o1 = __shfl_xor(c1, off), o2 = __shfl_xor(c2, off), o3 = __shfl_xor(c3, off);
        merge3(c1, c2, c3, o1, o2, o3);
      }
      if (cl == 0)
        cmb[(wr * 64 + m * 16 + g * 4 + r) * 2 + wc] = make_uint4(c1, c2, c3, 0);
    }
  }
  __syncthreads();
  if (tid < 128) {
    uint4 A = cmb[tid * 2], B = cmb[tid * 2 + 1];
    u32 c1 = A.x, c2 = A.y, c3 = A.z;
    merge3(c1, c2, c3, B.x, B.y, B.z);
    partials[(size_t)ct * M_TOK + row0 + tid] = make_uint4(c1, c2, c3, 0);
  }
}

// ---------------- reduce: best-2 global, flag, enqueue in-band top-3 + markers ----------------
__global__ __launch_bounds__(256) void reduce_kernel(
    const uint4* __restrict__ partials, u64* __restrict__ bestkey2,
    u32* __restrict__ bkey1, int* __restrict__ fidx,
    uint2* __restrict__ queue, uint2* __restrict__ markers, int* __restrict__ cnts) {
  int t = blockIdx.x * 256 + threadIdx.x;
  if (t >= M_TOK) return;
  u32 b1 = 0xFFFFFFFFu, b2 = 0xFFFFFFFFu;
  int bidx = 0;
  for (int ct = 0; ct < 64; ++ct) {
    uint4 e = partials[(size_t)ct * M_TOK + t];
    if (e.x < b1) {
      b2 = min(b1, min(b2, e.y));
      b1 = e.x;
      bidx = ct * 128 + (int)(e.x & 127u);
    } else {
      b2 = min(b2, e.x);
    }
  }
  fidx[t] = bidx;
  bestkey2[t] = ~0ULL;     // ws not re-poisoned between replays: init every launch
  bkey1[t] = b1;
  if (qval(b2) - qval(b1) < BAND) {
    const float thr = qval(b1) + BAND;
    for (int ct = 0; ct < 64; ++ct) {       // pass 2 (L2-hot)
      uint4 e = partials[(size_t)ct * M_TOK + t];
      if (qval(e.z) <= thr) {               // 3rd in band: hidden 4th possible ->
        int i = atomicAdd(&cnts[1], 1);     // exact rescan covers whole block
        if (i < MCAP) markers[i] = make_uint2((u32)t, (u32)ct);
      } else {
        if (qval(e.x) <= thr) {
          int i = atomicAdd(&cnts[0], 1);
          if (i < QCAP) queue[i] = make_uint2((u32)t, (u32)(ct * 128 + (e.x & 127u)));
        }
        if (qval(e.y) <= thr) {
          int i = atomicAdd(&cnts[0], 1);
          if (i < QCAP) queue[i] = make_uint2((u32)t, (u32)(ct * 128 + (e.y & 127u)));
        }
      }
    }
  }
}

// ---------------- rescan (rare): bit-identical i8 scores for marked blocks ----------------
__global__ __launch_bounds__(256) void rescan_kernel(
    const char* __restrict__ Xq, const char* __restrict__ Wq,
    const float* __restrict__ wnorm, const u32* __restrict__ bkey1,
    const uint2* __restrict__ markers, const int* __restrict__ cnts,
    uint2* __restrict__ queue, int* __restrict__ qcnt) {
  const int nm = min(cnts[1], MCAP);
  const int wid = (int)(blockIdx.x * 4 + (threadIdx.x >> 6));
  const int lane = threadIdx.x & 63;
  for (int i = wid; i < nm; i += (int)gridDim.x * 4) {
    const uint2 mk = markers[i];
    const int t = (int)mk.x, ct = (int)mk.y;
    const float thr = qval(bkey1[t]) + BAND;
    const int* xrow = (const int*)(Xq + (size_t)t * D_K);
    #pragma unroll
    for (int h = 0; h < 2; ++h) {
      const int j = ct * 128 + h * 64 + lane;
      const int* wrow = (const int*)(Wq + (size_t)j * D_K);
      int dot = 0;
      for (int kw = 0; kw < 128; ++kw) dot += dp4(xrow[kw], wrow[kw]);
      float score = fmaf((float)dot, M2C, wnorm[j] + WOFF);
      u32 key = (__float_as_uint(score) & QMASK);   // same quantized grid
      if (qval(key) <= thr) {
        int qi = atomicAdd(qcnt, 1);
        if (qi < QCAP) queue[qi] = make_uint2((u32)t, (u32)j);
      }
    }
  }
}

// ---------------- fixup2: one wave per (token,cand), exact f32 ----------------
__global__ __launch_bounds__(256) void fixup2_kernel(
    const float* __restrict__ xs, const float* __restrict__ w,
    const float* __restrict__ wnorm, const uint2* __restrict__ queue,
    const int* __restrict__ cnts, u64* __restrict__ bestkey2) {
  const int total = min(cnts[0], QCAP);
  const int wid = (int)(blockIdx.x * 4 + (threadIdx.x >> 6));
  const int lane = threadIdx.x & 63;
  for (int i = wid; i < total; i += (int)gridDim.x * 4) {
    const uint2 e = queue[i];
    const int t = (int)e.x, j = (int)e.y;
    const float4* xr = (const float4*)(xs + (size_t)t * D_K);
    const float4* wr = (const float4*)(w + (size_t)j * D_K);
    float4 a0 = xr[lane * 2], a1 = xr[lane * 2 + 1];
    float4 b0 = wr[lane * 2], b1 = wr[lane * 2 + 1];
    float s = a0.x*b0.x + a0.y*b0.y + a0.z*b0.z + a0.w*b0.w
            + a1.x*b1.x + a1.y*b1.y + a1.z*b1.z + a1.w*b1.w;
    #pragma unroll
    for (int off = 32; off; off >>= 1) s += __shfl_xor(s, off);
    if (lane == 0) {
      float score = wnorm[j] - 2.0f * s;
      u64 k = ((u64)map_f(score) << 32) | (u32)j;
      atomicMin(&bestkey2[t], k);
    }
  }
}

// ---------------- gather: out = xs + (W[idx] - xs)  (mimic ref arithmetic) ----------------
__global__ __launch_bounds__(256) void gather_kernel(const float* __restrict__ xs,
                                                     const float* __restrict__ w,
                                                     const int* __restrict__ fidx,
                                                     const u64* __restrict__ bestkey2,
                                                     float* __restrict__ out) {
  int e = blockIdx.x * 256 + threadIdx.x;
  int row = e >> 7, off = e & 127;
  u64 bk = bestkey2[row];
  int idx = (bk != ~0ULL) ? (int)(bk & 0xFFFFFFFFULL) : fidx[row];
  float4 xv = ((const float4*)(xs + (size_t)row * D_K))[off];
  float4 wv = ((const float4*)(w  + (size_t)idx * D_K))[off];
  float4 o;
  o.x = xv.x + (wv.x - xv.x);
  o.y = xv.y + (wv.y - xv.y);
  o.z = xv.z + (wv.z - xv.z);
  o.w = xv.w + (wv.w - xv.w);
  ((float4*)out)[e] = o;
}

extern "C" void kernel_launch(void* const* d_in, const int* in_sizes, int n_in,
                              void* d_out, int out_size, void* d_ws, size_t ws_size,
                              hipStream_t stream) {
  const float* xs = (const float*)d_in[0];
  const float* w  = (const float*)d_in[1];
  float* out = (float*)d_out;

  // ws layout (~62 MB; ws proven >= 85 MB in R2)
  char* p = (char*)d_ws;
  char*  Xq       = p;                       p += (size_t)M_TOK * D_K;        // 16 MB
  char*  Wq       = p;                       p += (size_t)N_EMB * D_K;        //  4 MB
  float* wnorm    = (float*)p;               p += (size_t)N_EMB * 4;
  uint4* partials = (uint4*)p;               p += (size_t)64 * M_TOK * 16;    // 32 MB
  int*   fidx     = (int*)p;                 p += (size_t)M_TOK * 4;
  u64*   bestkey2 = (u64*)p;                 p += (size_t)M_TOK * 8;
  u32*   bkey1    = (u32*)p;                 p += (size_t)M_TOK * 4;
  uint2* queue    = (uint2*)p;               p += (size_t)QCAP * 8;           //  8 MB
  uint2* markers  = (uint2*)p;               p += (size_t)MCAP * 8;
  int*   cnts     = (int*)p;                                                  // [cq, cm]

  quant_x_kernel<<<(M_TOK * D_K / 16) / 256, 256, 0, stream>>>(xs, Xq, M_TOK * D_K / 16);
  quant_w_kernel<<<N_EMB / 4, 256, 0, stream>>>(w, Wq, wnorm, cnts);
  dist_mfma_kernel<<<(M_TOK / 128) * (N_EMB / 128), 256, 0, stream>>>(Xq, Wq, wnorm, partials);
  reduce_kernel<<<M_TOK / 256, 256, 0, stream>>>(partials, bestkey2, bkey1, fidx,
                                                 queue, markers, cnts);
  rescan_kernel<<<256, 256, 0, stream>>>(Xq, Wq, wnorm, bkey1, markers, cnts,
                                         queue, &cnts[0]);
  fixup2_kernel<<<2048, 256, 0, stream>>>(xs, w, wnorm, queue, cnts, bestkey2);
  gather_kernel<<<(M_TOK * (D_K / 4)) / 256, 256, 0, stream>>>(xs, w, fidx, bestkey2, out);
}

// Round 17
// 363.451 us; speedup vs baseline: 1.7366x; 1.7366x over previous
//
#include <hip/hip_runtime.h>

// VQ codebook nearest-neighbor: xs [32768,512] f32, W [8192,512] f32
// out[i] = W[argmin_j ||xs_i - W_j||^2]
//
// R17: R13's proven i8 dist kernel (257us, 0 conflicts, best-2 partials)
//      + single wave-owned tail kernel: one wave per token does
//      {global best-2 butterfly -> if flagged: exact f32 dots over in-band
//      candidates (singles via ballot; full 128-code exact scan for blocks
//      whose 2nd-best is in band => hidden-3rd+ covered exactly)}.
//      No atomics, no LDS, no extra kernels. BAND 5.5 (R13/R15-proven).

#define M_TOK 32768
#define N_EMB 8192
#define D_K   512
#define WOFF  2048.0f
#define QMASK 0xFFFFFF80u     // 7 low bits = local col (128-wide tile)
#define BAND  5.5f
#define NT    8               // K-tiles of 64 (i8)
#define SCALE 22.6786f        // 127/5.6
#define M2C   (-2.0f / (SCALE * SCALE))

typedef __attribute__((ext_vector_type(4))) int   i32x4;
typedef unsigned long long u64;
typedef unsigned int u32;

__device__ __forceinline__ void gload16(const void* g, void* l) {
  __builtin_amdgcn_global_load_lds(
      (const __attribute__((address_space(1))) unsigned int*)g,
      (__attribute__((address_space(3))) unsigned int*)l, 16, 0, 0);
}

__device__ __forceinline__ u32 map_f(float f) {   // exact order-preserving
  u32 u = __float_as_uint(f);
  return u ^ ((u & 0x80000000u) ? 0xFFFFFFFFu : 0x80000000u);
}
__device__ __forceinline__ float qval(u32 key) {  // quantized approx value
  return __uint_as_float(key & QMASK) - WOFF;
}
__device__ __forceinline__ int q8(float x) {
  int v = __float2int_rn(x * SCALE);
  return v < -127 ? -127 : (v > 127 ? 127 : v);
}

// ---------------- X: f32 -> i8 ----------------
__global__ __launch_bounds__(256) void quant_x_kernel(const float* __restrict__ src,
                                                      char* __restrict__ dst, int n16) {
  int e = blockIdx.x * 256 + threadIdx.x;
  if (e >= n16) return;
  const float4* s4 = (const float4*)src + (size_t)e * 4;
  char out[16];
  #pragma unroll
  for (int i = 0; i < 4; ++i) {
    float4 v = s4[i];
    out[i * 4 + 0] = (char)q8(v.x);
    out[i * 4 + 1] = (char)q8(v.y);
    out[i * 4 + 2] = (char)q8(v.z);
    out[i * 4 + 3] = (char)q8(v.w);
  }
  ((int4*)dst)[e] = *(const int4*)out;
}

// ---------------- W: quantize + exact ||w||^2 ----------------
__global__ __launch_bounds__(256) void quant_w_kernel(const float* __restrict__ w,
                                                      char* __restrict__ Wq,
                                                      float* __restrict__ wnorm) {
  const int row  = blockIdx.x * 4 + (threadIdx.x >> 6);
  const int lane = threadIdx.x & 63;
  const float4* wr = (const float4*)(w + (size_t)row * D_K);
  float4 v0 = wr[lane * 2], v1 = wr[lane * 2 + 1];
  char out[8];
  out[0] = (char)q8(v0.x); out[1] = (char)q8(v0.y);
  out[2] = (char)q8(v0.z); out[3] = (char)q8(v0.w);
  out[4] = (char)q8(v1.x); out[5] = (char)q8(v1.y);
  out[6] = (char)q8(v1.z); out[7] = (char)q8(v1.w);
  *(int2*)(Wq + (size_t)row * D_K + lane * 8) = *(const int2*)out;
  float s = v0.x*v0.x + v0.y*v0.y + v0.z*v0.z + v0.w*v0.w
          + v1.x*v1.x + v1.y*v1.y + v1.z*v1.z + v1.w*v1.w;
  #pragma unroll
  for (int off = 32; off; off >>= 1) s += __shfl_xor(s, off);
  if (lane == 0) wnorm[row] = s;
}

// ---------------- i8 approx distance + per-block best-2 (R13, unchanged) ----------------
__global__ __launch_bounds__(256, 3) void dist_mfma_kernel(
    const char* __restrict__ Xq, const char* __restrict__ Wq,
    const float* __restrict__ wnorm, uint2* __restrict__ partials) {
  __shared__ char smem[32768];   // buf b at b*16384: [A 8KB | B 8KB]

  int bid = (int)blockIdx.x;
  const int swz = (bid & 7) * 2048 + (bid >> 3);   // XCD swizzle (16384 % 8 == 0)
  const int rt = swz & 255, ct = swz >> 8;          // rt fast -> B-panel L2-hot
  const int row0 = rt * 128, col0 = ct * 128;

  const int tid  = threadIdx.x;
  const int w    = tid >> 6, lane = tid & 63;
  const int wr   = w >> 1,  wc   = w & 1;           // 2x2 wave grid
  const int g    = lane >> 4, cl = lane & 15;

  const char* gA = Xq + (size_t)row0 * D_K;         // row = 512 B
  const char* gB = Wq + (size_t)col0 * D_K;

  int srcoff[2];
  #pragma unroll
  for (int q = 0; q < 2; ++q) {
    const int c = q * 256 + tid;
    const int r = c >> 2;
    srcoff[q] = r * 512 + (((c & 3) ^ ((r >> 1) & 3)) * 16);
  }

  int offA[4], offB[4];
  #pragma unroll
  for (int m = 0; m < 4; ++m) {
    const int rl = wr * 64 + m * 16 + cl;
    offA[m] = rl * 64 + ((g ^ ((rl >> 1) & 3)) * 16);
  }
  #pragma unroll
  for (int n = 0; n < 4; ++n) {
    const int rl = wc * 64 + n * 16 + cl;
    offB[n] = 8192 + rl * 64 + ((g ^ ((rl >> 1) & 3)) * 16);
  }

  #define STG(bo, kt)                                                          \
    { _Pragma("unroll") for (int q = 0; q < 2; ++q)                            \
        gload16(gA + srcoff[q] + (kt) * 64,                                    \
                smem + (bo) + q * 4096 + w * 1024);                            \
      _Pragma("unroll") for (int q = 0; q < 2; ++q)                            \
        gload16(gB + srcoff[q] + (kt) * 64,                                    \
                smem + (bo) + 8192 + q * 4096 + w * 1024); }

  i32x4 acc[4][4];
  #pragma unroll
  for (int i = 0; i < 4; i++)
    #pragma unroll
    for (int j = 0; j < 4; j++) acc[i][j] = (i32x4)(0);

  STG(0, 0);
  __syncthreads();

  for (int t = 0; t < NT; ++t) {
    const int rb = (t & 1) * 16384, sb = rb ^ 16384;
    if (t < NT - 1) STG(sb, t + 1);

    i32x4 a[4], b[4];
    #pragma unroll
    for (int m = 0; m < 4; ++m) a[m] = *(const i32x4*)(smem + rb + offA[m]);
    #pragma unroll
    for (int n = 0; n < 4; ++n) b[n] = *(const i32x4*)(smem + rb + offB[n]);

    #pragma unroll
    for (int m = 0; m < 4; ++m)
      #pragma unroll
      for (int n = 0; n < 4; ++n)
        acc[m][n] = __builtin_amdgcn_mfma_i32_16x16x64_i8(a[m], b[n], acc[m][n], 0, 0, 0);

    __syncthreads();
  }
  #undef STG

  float wnp[4];
  u32 colb[4];
  #pragma unroll
  for (int n = 0; n < 4; ++n) {
    const int colL = wc * 64 + n * 16 + cl;
    wnp[n]  = wnorm[col0 + colL] + WOFF;
    colb[n] = (u32)colL;
  }

  uint2* cmb = (uint2*)smem;

  #pragma unroll
  for (int m = 0; m < 4; ++m) {
    #pragma unroll
    for (int r = 0; r < 4; ++r) {
      float s0 = fmaf((float)acc[m][0][r], M2C, wnp[0]);
      float s1 = fmaf((float)acc[m][1][r], M2C, wnp[1]);
      float s2 = fmaf((float)acc[m][2][r], M2C, wnp[2]);
      float s3 = fmaf((float)acc[m][3][r], M2C, wnp[3]);
      u32 k0 = (__float_as_uint(s0) & QMASK) | colb[0];
      u32 k1 = (__float_as_uint(s1) & QMASK) | colb[1];
      u32 k2 = (__float_as_uint(s2) & QMASK) | colb[2];
      u32 k3 = (__float_as_uint(s3) & QMASK) | colb[3];
      u32 pa = min(k0, k1), pb = max(k0, k1);
      u32 pc = min(k2, k3), pd = max(k2, k3);
      u32 c1 = min(pa, pc);
      u32 c2 = min(max(pa, pc), min(pb, pd));
      #pragma unroll
      for (int off = 1; off < 16; off <<= 1) {
        u32 o1 = __shfl_xor(c1, off), o2 = __shfl_xor(c2, off);
        u32 n1 = min(c1, o1);
        c2 = min(min(c2, o2), max(c1, o1));
        c1 = n1;
      }
      if (cl == 0) cmb[(wr * 64 + m * 16 + g * 4 + r) * 2 + wc] = make_uint2(c1, c2);
    }
  }
  __syncthreads();
  if (tid < 128) {
    uint2 A = cmb[tid * 2], B = cmb[tid * 2 + 1];
    u32 c1 = min(A.x, B.x);
    u32 c2 = min(max(A.x, B.x), min(A.y, B.y));
    partials[(size_t)ct * M_TOK + row0 + tid] = make_uint2(c1, c2);
  }
}

// ---------------- wave-owned argmin + exact fixup (one wave per token) ----------------
// lane l holds block l's best-2. Butterfly -> global best-2. If flagged:
// exact f32 dots for in-band singles (ballot) and full 128-code exact scans
// for blocks whose 2nd-best is in band (covers hidden 3rd+ exactly).
__global__ __launch_bounds__(256) void argmin_wave_kernel(
    const uint2* __restrict__ partials, const float* __restrict__ xs,
    const float* __restrict__ w, const float* __restrict__ wnorm,
    int* __restrict__ fidx) {
  const int t = blockIdx.x * 4 + (threadIdx.x >> 6);
  const int lane = threadIdx.x & 63;

  const uint2 e = partials[(size_t)lane * M_TOK + t];
  u32 b1 = e.x, b2 = e.y;
  #pragma unroll
  for (int off = 1; off < 64; off <<= 1) {
    u32 o1 = __shfl_xor(b1, off), o2 = __shfl_xor(b2, off);
    u32 n1 = min(b1, o1);
    b2 = min(min(b2, o2), max(b1, o1));
    b1 = n1;
  }
  // b1,b2 uniform. Owning block = lowest lane with e.x == b1 (first-occurrence).
  const int bl = __ffsll(__ballot(e.x == b1)) - 1;
  const int bidx = bl * 128 + (int)(b1 & 127u);

  if (qval(b2) - qval(b1) >= BAND) {
    if (lane == 0) fidx[t] = bidx;
    return;
  }

  // flagged: exact re-rank of the in-band candidate set
  const float thr = qval(b1) + BAND;
  const bool in2 = qval(e.y) <= thr;                  // block needs full scan
  const bool in1 = (qval(e.x) <= thr) && !in2;        // single candidate
  u64 mask1 = __ballot(in1);
  u64 mask2 = __ballot(in2);

  const float4* xr = (const float4*)(xs + (size_t)t * D_K);
  const float4 xv0 = xr[lane * 2], xv1 = xr[lane * 2 + 1];

  u64 best = ~0ULL;
  #define EXACT_DOT(j)                                                         \
    {                                                                          \
      const float4* wrp = (const float4*)(w + (size_t)(j) * D_K);              \
      float4 w0 = wrp[lane * 2], w1 = wrp[lane * 2 + 1];                       \
      float s = xv0.x*w0.x + xv0.y*w0.y + xv0.z*w0.z + xv0.w*w0.w              \
              + xv1.x*w1.x + xv1.y*w1.y + xv1.z*w1.z + xv1.w*w1.w;             \
      _Pragma("unroll")                                                        \
      for (int off = 32; off; off >>= 1) s += __shfl_xor(s, off);              \
      float score = wnorm[j] - 2.0f * s;                                       \
      u64 k = ((u64)map_f(score) << 32) | (u32)(j);                            \
      best = k < best ? k : best;                                              \
    }

  while (mask1) {
    const int l = __ffsll(mask1) - 1;
    mask1 &= mask1 - 1;
    const u32 key = __shfl(e.x, l);
    const int j = l * 128 + (int)(key & 127u);
    EXACT_DOT(j);
  }
  while (mask2) {
    const int l = __ffsll(mask2) - 1;
    mask2 &= mask2 - 1;
    for (int c = 0; c < 128; ++c) {
      const int j = l * 128 + c;
      EXACT_DOT(j);
    }
  }
  #undef EXACT_DOT

  if (lane == 0) fidx[t] = (int)(best & 0xFFFFFFFFULL);
}

// ---------------- gather: out = xs + (W[idx] - xs)  (mimic ref arithmetic) ----------------
__global__ __launch_bounds__(256) void gather_kernel(const float* __restrict__ xs,
                                                     const float* __restrict__ w,
                                                     const int* __restrict__ fidx,
                                                     float* __restrict__ out) {
  int e = blockIdx.x * 256 + threadIdx.x;
  int row = e >> 7, off = e & 127;
  float4 xv = ((const float4*)(xs + (size_t)row * D_K))[off];
  float4 wv = ((const float4*)(w  + (size_t)fidx[row] * D_K))[off];
  float4 o;
  o.x = xv.x + (wv.x - xv.x);
  o.y = xv.y + (wv.y - xv.y);
  o.z = xv.z + (wv.z - xv.z);
  o.w = xv.w + (wv.w - xv.w);
  ((float4*)out)[e] = o;
}

extern "C" void kernel_launch(void* const* d_in, const int* in_sizes, int n_in,
                              void* d_out, int out_size, void* d_ws, size_t ws_size,
                              hipStream_t stream) {
  const float* xs = (const float*)d_in[0];
  const float* w  = (const float*)d_in[1];
  float* out = (float*)d_out;

  // ws layout (~36 MB; ws proven >= 85 MB in R2)
  char* p = (char*)d_ws;
  char*  Xq       = p;                       p += (size_t)M_TOK * D_K;        // 16 MB
  char*  Wq       = p;                       p += (size_t)N_EMB * D_K;        //  4 MB
  float* wnorm    = (float*)p;               p += (size_t)N_EMB * 4;
  uint2* partials = (uint2*)p;               p += (size_t)64 * M_TOK * 8;     // 16 MB
  int*   fidx     = (int*)p;

  quant_x_kernel<<<(M_TOK * D_K / 16) / 256, 256, 0, stream>>>(xs, Xq, M_TOK * D_K / 16);
  quant_w_kernel<<<N_EMB / 4, 256, 0, stream>>>(w, Wq, wnorm);
  dist_mfma_kernel<<<(M_TOK / 128) * (N_EMB / 128), 256, 0, stream>>>(Xq, Wq, wnorm, partials);
  argmin_wave_kernel<<<M_TOK / 4, 256, 0, stream>>>(partials, xs, w, wnorm, fidx);
  gather_kernel<<<(M_TOK * (D_K / 4)) / 256, 256, 0, stream>>>(xs, w, fidx, out);
}